// Round 5
// baseline (361.120 us; speedup 1.0000x reference)
//
#include <hip/hip_runtime.h>

typedef unsigned short u16t;
typedef __bf16 bf16x8 __attribute__((ext_vector_type(8)));
typedef float  f32x4  __attribute__((ext_vector_type(4)));
typedef float  f32x16 __attribute__((ext_vector_type(16)));
typedef unsigned u32x2 __attribute__((ext_vector_type(2)));
typedef unsigned u32x4 __attribute__((ext_vector_type(4)));

#define DEV __device__ __forceinline__

DEV u16t f32_to_bf16(float f) {
    unsigned u = __float_as_uint(f);
    unsigned r = (u + 0x7FFFu + ((u >> 16) & 1u)) >> 16;   // RNE
    return (u16t)r;
}
DEV float bf16_to_f32(u16t u) { return __uint_as_float((unsigned)u << 16); }

DEV unsigned cvt_pk_bf16(float lo, float hi) {
    unsigned r;
    asm("v_cvt_pk_bf16_f32 %0, %1, %2" : "=v"(r) : "v"(lo), "v"(hi));
    return r;
}

DEV float gelu_exact(float x) {
    return 0.5f * x * (1.0f + erff(x * 0.70710678118654752f));
}

// XOR swizzles: rows of 128 B / 64 B spread across 8/4 16-B slots (involutions)
DEV int swzK(int b) { return b ^ (((b >> 7) & 7) << 4); }
DEV int swzV(int b) { return b ^ (((b >> 6) & 3) << 4); }

// raw barrier with explicit full VMEM drain (no compiler-implicit waits)
DEV void wait_and_barrier() {
    asm volatile("s_waitcnt vmcnt(0)" ::: "memory");
    __builtin_amdgcn_sched_barrier(0);
    __builtin_amdgcn_s_barrier();
    __builtin_amdgcn_sched_barrier(0);
}

// ---------------------------------------------------------------- LayerNorm
__global__ __launch_bounds__(256)
void ln_kernel(const float* __restrict__ x, const float* __restrict__ g,
               const float* __restrict__ b, u16t* __restrict__ out)
{
    const int row = blockIdx.x;
    const int t = threadIdx.x;
    const float* xr = x + (size_t)row * 768;
    float v0 = xr[t], v1 = xr[t + 256], v2 = xr[t + 512];
    float s = v0 + v1 + v2;
    float s2 = v0 * v0 + v1 * v1 + v2 * v2;
#pragma unroll
    for (int off = 32; off > 0; off >>= 1) {
        s  += __shfl_xor(s, off);
        s2 += __shfl_xor(s2, off);
    }
    __shared__ float sm[8];
    const int w = t >> 6;
    if ((t & 63) == 0) { sm[w] = s; sm[4 + w] = s2; }
    __syncthreads();
    s  = sm[0] + sm[1] + sm[2] + sm[3];
    s2 = sm[4] + sm[5] + sm[6] + sm[7];
    const float mu  = s * (1.0f / 768.0f);
    const float var = fmaxf(s2 * (1.0f / 768.0f) - mu * mu, 0.0f);
    const float rst = rsqrtf(var + 1e-5f);
    u16t* o = out + (size_t)row * 768;
    o[t]       = f32_to_bf16((v0 - mu) * rst * g[t]       + b[t]);
    o[t + 256] = f32_to_bf16((v1 - mu) * rst * g[t + 256] + b[t + 256]);
    o[t + 512] = f32_to_bf16((v2 - mu) * rst * g[t + 512] + b[t + 512]);
}

// ---------------------------------------------------- transpose f32 -> bf16
__global__ __launch_bounds__(256)
void transpose_cast(const float* __restrict__ in, u16t* __restrict__ out,
                    int R, int C)
{
    __shared__ float tile[64][65];
    const int c0 = blockIdx.x * 64, r0 = blockIdx.y * 64;
    const int t = threadIdx.x;
#pragma unroll
    for (int j = 0; j < 16; ++j) {
        const int idx = j * 256 + t;
        const int rl = idx >> 6, cl = idx & 63;
        tile[rl][cl] = in[(size_t)(r0 + rl) * C + c0 + cl];
    }
    __syncthreads();
#pragma unroll
    for (int j = 0; j < 16; ++j) {
        const int idx = j * 256 + t;
        const int cl = idx >> 6, rl = idx & 63;
        out[(size_t)(c0 + cl) * R + r0 + rl] = f32_to_bf16(tile[rl][cl]);
    }
}

// ------------------------------------------------------------------- GEMM
// MODE 0: store f32. MODE 1: +res (+bias), store f32. MODE 2: gelu(acc+bias),
// store bf16. MODE 3: qkv epilogue -> Q,K [B*H,N,64] bf16 + VT [B*H,64,N].
template <int MODE>
__global__ __launch_bounds__(256)
void gemm_kernel(const u16t* __restrict__ A, const u16t* __restrict__ BT,
                 float* __restrict__ Cf, u16t* __restrict__ Cb,
                 const float* __restrict__ bias, const float* __restrict__ res,
                 u16t* __restrict__ Qo, u16t* __restrict__ Ko,
                 u16t* __restrict__ VTo,
                 int M, int Nn, int K)
{
    __shared__ u16t Asm[128 * 64];
    __shared__ u16t Bsm[128 * 64];
    const int t = threadIdx.x;
    const int w = t >> 6, lane = t & 63;
    const int l16 = lane & 15, lhi = lane >> 4;
    const int wr = w >> 1, wc = w & 1;
    const int m0 = blockIdx.x * 128, n0 = blockIdx.y * 128;

    const f32x4 fz = {0.f, 0.f, 0.f, 0.f};
    f32x4 acc[4][4];
#pragma unroll
    for (int i = 0; i < 4; ++i)
#pragma unroll
        for (int j = 0; j < 4; ++j) acc[i][j] = fz;

    const int rowA = lane >> 3;
    const int colb = (lane & 7) * 16;

    for (int kt = 0; kt < K; kt += 64) {
#pragma unroll
        for (int i = 0; i < 4; ++i) {
            const int seg = w * 4 + i;
            const char* ga = (const char*)A +
                ((size_t)(m0 + seg * 8 + rowA) * K + kt) * 2 + colb;
            __builtin_amdgcn_global_load_lds(
                (const __attribute__((address_space(1))) void*)ga,
                (__attribute__((address_space(3))) void*)((char*)Asm + seg * 1024),
                16, 0, 0);
            const char* gb = (const char*)BT +
                ((size_t)(n0 + seg * 8 + rowA) * K + kt) * 2 + colb;
            __builtin_amdgcn_global_load_lds(
                (const __attribute__((address_space(1))) void*)gb,
                (__attribute__((address_space(3))) void*)((char*)Bsm + seg * 1024),
                16, 0, 0);
        }
        __syncthreads();
#pragma unroll
        for (int kk = 0; kk < 64; kk += 32) {
            bf16x8 af[4], bfv[4];
#pragma unroll
            for (int i = 0; i < 4; ++i)
                af[i] = *reinterpret_cast<const bf16x8*>(
                    Asm + (64 * wr + 16 * i + l16) * 64 + kk + 8 * lhi);
#pragma unroll
            for (int j = 0; j < 4; ++j)
                bfv[j] = *reinterpret_cast<const bf16x8*>(
                    Bsm + (64 * wc + 16 * j + l16) * 64 + kk + 8 * lhi);
#pragma unroll
            for (int i = 0; i < 4; ++i)
#pragma unroll
                for (int j = 0; j < 4; ++j)
                    acc[i][j] = __builtin_amdgcn_mfma_f32_16x16x32_bf16(
                        af[i], bfv[j], acc[i][j], 0, 0, 0);
        }
        __syncthreads();
    }

    const int rb = m0 + 64 * wr + 4 * lhi;
    const int cb = n0 + 64 * wc + l16;

    if (MODE == 3) {
        const int qi = n0 / 768;                 // uniform per block
        const int b = rb >> 11;
        const int nn0 = rb & 2047;
#pragma unroll
        for (int j = 0; j < 4; ++j) {
            const int c = cb - qi * 768 + 16 * j;   // 0..767
            const int h = c >> 6, d = c & 63;
            if (qi < 2) {
                u16t* dst = (qi == 0) ? Qo : Ko;
                const size_t base = ((size_t)(b * 12 + h) * 2048 + nn0) * 64 + d;
#pragma unroll
                for (int i = 0; i < 4; ++i)
#pragma unroll
                    for (int r = 0; r < 4; ++r)
                        dst[base + (size_t)(16 * i + r) * 64] =
                            f32_to_bf16(acc[i][j][r]);
            } else {
                u16t* dst = VTo + ((size_t)(b * 12 + h) * 64 + d) * 2048 + nn0;
#pragma unroll
                for (int i = 0; i < 4; ++i) {
                    u32x2 pr;
                    pr[0] = cvt_pk_bf16(acc[i][j][0], acc[i][j][1]);
                    pr[1] = cvt_pk_bf16(acc[i][j][2], acc[i][j][3]);
                    *reinterpret_cast<u32x2*>(dst + 16 * i) = pr;
                }
            }
        }
        return;
    }

#pragma unroll
    for (int i = 0; i < 4; ++i) {
#pragma unroll
        for (int j = 0; j < 4; ++j) {
#pragma unroll
            for (int r = 0; r < 4; ++r) {
                const int row = rb + 16 * i + r;
                const int col = cb + 16 * j;
                float v = acc[i][j][r];
                if (MODE == 0) {
                    Cf[(size_t)row * Nn + col] = v;
                } else if (MODE == 1) {
                    v += res[(size_t)row * Nn + col];
                    if (bias) v += bias[col];
                    Cf[(size_t)row * Nn + col] = v;
                } else if (MODE == 2) {
                    v = gelu_exact(v + bias[col]);
                    Cb[(size_t)row * Nn + col] = f32_to_bf16(v);
                }
            }
        }
    }
}

// ------------------------------------------------------- flash attention
// Swapped-operand 32x32 MFMA; double-buffered K/V LDS with one raw barrier
// per 32-k tile (+vmcnt(0) drain); bias reg-prefetched one tile ahead.
// Max-free softmax; 4-way k-split. grid (16, B*H, 4), block 256.
__global__ __launch_bounds__(256, 4)
void attn_kernel(const u16t* __restrict__ Q, const u16t* __restrict__ K,
                 const u16t* __restrict__ VT, const float* __restrict__ bias,
                 u16t* __restrict__ Opart, float* __restrict__ Lpart)
{
    const int SEQ = 2048;
    const int bh = blockIdx.y, h = bh % 12;
    const int ks = blockIdx.z;
    const int t = threadIdx.x;
    const int w = t >> 6, lane = t & 63;
    const int l32 = lane & 31, hi = lane >> 5;
    const int q = blockIdx.x * 128 + w * 32 + l32;

    // [0,4K) K0 | [4K,8K) V0 | [8K,12K) K1 | [12K,16K) V1
    __shared__ char smem[16384];

    // Q B-frags in regs: Q[q][dseg*16 + 8*hi + j]
    const u16t* qp = Q + ((size_t)bh * SEQ + q) * 64 + 8 * hi;
    bf16x8 qf[4];
#pragma unroll
    for (int dseg = 0; dseg < 4; ++dseg)
        qf[dseg] = *reinterpret_cast<const bf16x8*>(qp + dseg * 16);

    const char* kglob = (const char*)K + (size_t)bh * SEQ * 128;   // 128B rows
    const char* vglob = (const char*)VT + (size_t)bh * 64 * 4096;  // 4KB rows
    const float* brow = bias + ((size_t)h * SEQ + q) * SEQ + 4 * hi;

    // loop-invariant swizzled LDS read offsets
    int koff[4];
#pragma unroll
    for (int i = 0; i < 4; ++i) koff[i] = swzK(l32 * 128 + i * 32 + 16 * hi);
    const int voff00 = swzV(l32 * 64 + 16 * hi);
    const int voff01 = swzV(l32 * 64 + 32 + 16 * hi);
    const int voff10 = swzV((32 + l32) * 64 + 16 * hi);
    const int voff11 = swzV((32 + l32) * 64 + 32 + 16 * hi);

    // loop-invariant staging offsets (pre-swizzled global source, linear LDS)
    const int gk = w * 1024 + 16 * lane;
    const int tbK = gk ^ (((gk >> 7) & 7) << 4);
    const int tbV = gk ^ (((gk >> 6) & 3) << 4);

    auto stage = [&](int bufb, int k0) {
        const char* sk = kglob + (size_t)k0 * 128 + tbK;
        __builtin_amdgcn_global_load_lds(
            (const __attribute__((address_space(1))) void*)sk,
            (__attribute__((address_space(3))) void*)(smem + bufb + w * 1024),
            16, 0, 0);
        const char* sv = vglob + (size_t)(tbV >> 6) * 4096 +
                         (size_t)k0 * 2 + (tbV & 63);
        __builtin_amdgcn_global_load_lds(
            (const __attribute__((address_space(1))) void*)sv,
            (__attribute__((address_space(3))) void*)(smem + bufb + 4096 + w * 1024),
            16, 0, 0);
    };
    auto bload = [&](f32x4 (&bv)[4], int k0) {
#pragma unroll
        for (int g = 0; g < 4; ++g)
            bv[g] = *reinterpret_cast<const f32x4*>(brow + k0 + 8 * g);
    };

    f32x16 o0, o1;
#pragma unroll
    for (int i = 0; i < 16; ++i) { o0[i] = 0.f; o1[i] = 0.f; }
    float lsum = 0.f;

    auto body = [&](int bufb, const f32x4 (&bv)[4]) {
        f32x16 st;
#pragma unroll
        for (int i = 0; i < 16; ++i) st[i] = 0.f;
#pragma unroll
        for (int dseg = 0; dseg < 4; ++dseg) {
            bf16x8 kf = *reinterpret_cast<const bf16x8*>(smem + bufb + koff[dseg]);
            st = __builtin_amdgcn_mfma_f32_32x32x16_bf16(kf, qf[dseg], st, 0, 0, 0);
        }
        unsigned pk[8];
#pragma unroll
        for (int i2 = 0; i2 < 8; ++i2) {
            const int ia = 2 * i2, ib = 2 * i2 + 1;
            const float pa = __expf(st[ia] * 0.125f + bv[ia >> 2][ia & 3]);
            const float pb = __expf(st[ib] * 0.125f + bv[ib >> 2][ib & 3]);
            lsum += pa + pb;
            pk[i2] = cvt_pk_bf16(pa, pb);
        }
        unsigned sx[8];
#pragma unroll
        for (int i2 = 0; i2 < 8; ++i2)
            sx[i2] = (unsigned)__shfl_xor((int)pk[i2], 32);
        union { unsigned u[4]; bf16x8 v; } B0, B1;
        B0.u[0] = hi ? sx[2] : pk[0];
        B0.u[1] = hi ? sx[3] : pk[1];
        B0.u[2] = hi ? pk[2] : sx[0];
        B0.u[3] = hi ? pk[3] : sx[1];
        B1.u[0] = hi ? sx[6] : pk[4];
        B1.u[1] = hi ? sx[7] : pk[5];
        B1.u[2] = hi ? pk[6] : sx[4];
        B1.u[3] = hi ? pk[7] : sx[5];
        const char* vb = smem + bufb + 4096;
        bf16x8 v00 = *reinterpret_cast<const bf16x8*>(vb + voff00);
        bf16x8 v01 = *reinterpret_cast<const bf16x8*>(vb + voff01);
        bf16x8 v10 = *reinterpret_cast<const bf16x8*>(vb + voff10);
        bf16x8 v11 = *reinterpret_cast<const bf16x8*>(vb + voff11);
        o0 = __builtin_amdgcn_mfma_f32_32x32x16_bf16(v00, B0.v, o0, 0, 0, 0);
        o0 = __builtin_amdgcn_mfma_f32_32x32x16_bf16(v01, B1.v, o0, 0, 0, 0);
        o1 = __builtin_amdgcn_mfma_f32_32x32x16_bf16(v10, B0.v, o1, 0, 0, 0);
        o1 = __builtin_amdgcn_mfma_f32_32x32x16_bf16(v11, B1.v, o1, 0, 0, 0);
    };

    const int kbeg = ks * 512, kend = kbeg + 512;

    f32x4 bvA[4];
    stage(0, kbeg);
    bload(bvA, kbeg);
    wait_and_barrier();

    for (int k0 = kbeg; k0 < kend; k0 += 64) {
        // even tile: consume buf0/bvA, prefetch buf1/bvB (k0+32 always valid)
        f32x4 bvB[4];
        stage(8192, k0 + 32);
        bload(bvB, k0 + 32);
        body(0, bvA);
        wait_and_barrier();
        // odd tile: consume buf1/bvB, prefetch buf0/bvA
        if (k0 + 64 < kend) { stage(0, k0 + 64); bload(bvA, k0 + 64); }
        body(8192, bvB);
        wait_and_barrier();
    }

    lsum += __shfl_xor(lsum, 32);

    u16t* op = Opart + ((size_t)(ks * 24 + bh) * SEQ + q) * 64;
#pragma unroll
    for (int dh = 0; dh < 2; ++dh) {
        const f32x16& o = dh ? o1 : o0;
#pragma unroll
        for (int g = 0; g < 4; ++g) {
            u32x2 pr;
            pr[0] = cvt_pk_bf16(o[4 * g], o[4 * g + 1]);
            pr[1] = cvt_pk_bf16(o[4 * g + 2], o[4 * g + 3]);
            *reinterpret_cast<u32x2*>(op + dh * 32 + 8 * g + 4 * hi) = pr;
        }
    }
    if (!hi)
        Lpart[(size_t)(ks * 24 + bh) * SEQ + q] = lsum;
}

// --------------------------------------------- combine k-split partials
__global__ __launch_bounds__(256)
void attn_combine(const u16t* __restrict__ Opart,
                  const float* __restrict__ Lpart, u16t* __restrict__ out)
{
    const int idx = blockIdx.x * 256 + threadIdx.x;   // 0 .. 24*2048*8
    const int dg = idx & 7;
    const int q = (idx >> 3) & 2047;
    const int bh = idx >> 14;
    const int b = bh / 12, h = bh % 12;
    const size_t base = ((size_t)bh * 2048 + q) * 64 + dg * 8;
    const size_t stride = (size_t)24 * 2048 * 64;
    float acc[8] = {0.f, 0.f, 0.f, 0.f, 0.f, 0.f, 0.f, 0.f};
    float l = 0.f;
#pragma unroll
    for (int j = 0; j < 4; ++j) {
        const u32x4 a = *reinterpret_cast<const u32x4*>(Opart + base + j * stride);
#pragma unroll
        for (int m = 0; m < 4; ++m) {
            acc[2 * m]     += bf16_to_f32((u16t)(a[m] & 0xFFFF));
            acc[2 * m + 1] += bf16_to_f32((u16t)(a[m] >> 16));
        }
        l += Lpart[(size_t)j * 24 * 2048 + bh * 2048 + q];
    }
    const float inv = 1.0f / l;
    u32x4 r;
#pragma unroll
    for (int m = 0; m < 4; ++m)
        r[m] = cvt_pk_bf16(acc[2 * m] * inv, acc[2 * m + 1] * inv);
    *reinterpret_cast<u32x4*>(
        out + ((size_t)(b * 2048 + q)) * 768 + h * 64 + dg * 8) = r;
}

// ------------------------------------------------------------------ launch
extern "C" void kernel_launch(void* const* d_in, const int* in_sizes, int n_in,
                              void* d_out, int out_size, void* d_ws, size_t ws_size,
                              hipStream_t stream)
{
    const float* x    = (const float*)d_in[0];
    const float* Wqkv = (const float*)d_in[1];
    const float* Wout = (const float*)d_in[2];
    const float* g1   = (const float*)d_in[3];
    const float* be1  = (const float*)d_in[4];
    const float* g2   = (const float*)d_in[5];
    const float* be2  = (const float*)d_in[6];
    const float* W1   = (const float*)d_in[7];
    const float* b1   = (const float*)d_in[8];
    const float* W2   = (const float*)d_in[9];
    const float* b2   = (const float*)d_in[10];
    const float* ab   = (const float*)d_in[11];
    float* outp = (float*)d_out;

    char* ws = (char*)d_ws;
    size_t off = 0;
    auto alloc = [&](size_t bytes) -> char* {
        char* p = ws + off;
        off += (bytes + 255) & ~(size_t)255;
        return p;
    };

    u16t* WqkvT = (u16t*)alloc((size_t)2304 * 768 * 2);
    u16t* WoutT = (u16t*)alloc((size_t)768 * 768 * 2);
    u16t* W1T   = (u16t*)alloc((size_t)3072 * 768 * 2);
    u16t* W2T   = (u16t*)alloc((size_t)768 * 3072 * 2);
    u16t* h1    = (u16t*)alloc((size_t)4096 * 768 * 2);
    u16t* Qb    = (u16t*)alloc((size_t)24 * 2048 * 64 * 2);
    u16t* Kb    = (u16t*)alloc((size_t)24 * 2048 * 64 * 2);
    u16t* VTb   = (u16t*)alloc((size_t)24 * 64 * 2048 * 2);
    u16t* attnb = (u16t*)alloc((size_t)4096 * 768 * 2);
    float* x1   = (float*)alloc((size_t)4096 * 768 * 4);
    u16t* h2    = (u16t*)alloc((size_t)4096 * 768 * 2);
    u16t* Opart = (u16t*)alloc((size_t)4 * 24 * 2048 * 64 * 2);
    float* Lpart = (float*)alloc((size_t)4 * 24 * 2048 * 4);
    u16t* act   = (u16t*)alloc((size_t)4096 * 3072 * 2);

    // weight prep
    transpose_cast<<<dim3(36, 12), 256, 0, stream>>>(Wqkv, WqkvT, 768, 2304);
    transpose_cast<<<dim3(12, 12), 256, 0, stream>>>(Wout, WoutT, 768, 768);
    transpose_cast<<<dim3(48, 12), 256, 0, stream>>>(W1,   W1T,   768, 3072);
    transpose_cast<<<dim3(12, 48), 256, 0, stream>>>(W2,   W2T,   3072, 768);

    // attention block
    ln_kernel<<<4096, 256, 0, stream>>>(x, g1, be1, h1);
    gemm_kernel<3><<<dim3(32, 18), 256, 0, stream>>>(
        h1, WqkvT, nullptr, nullptr, nullptr, nullptr, Qb, Kb, VTb,
        4096, 2304, 768);
    attn_kernel<<<dim3(16, 24, 4), 256, 0, stream>>>(Qb, Kb, VTb, ab, Opart, Lpart);
    attn_combine<<<(24 * 2048 * 8) / 256, 256, 0, stream>>>(Opart, Lpart, attnb);
    gemm_kernel<1><<<dim3(32, 6), 256, 0, stream>>>(
        attnb, WoutT, x1, nullptr, nullptr, x, nullptr, nullptr, nullptr,
        4096, 768, 768);

    // feed-forward block
    ln_kernel<<<4096, 256, 0, stream>>>(x1, g2, be2, h2);
    gemm_kernel<2><<<dim3(32, 24), 256, 0, stream>>>(
        h2, W1T, nullptr, act, b1, nullptr, nullptr, nullptr, nullptr,
        4096, 3072, 768);
    gemm_kernel<1><<<dim3(32, 6), 256, 0, stream>>>(
        act, W2T, outp, nullptr, b2, x1, nullptr, nullptr, nullptr,
        4096, 768, 3072);
}

// Round 6
// 269.265 us; speedup vs baseline: 1.3411x; 1.3411x over previous
//
#include <hip/hip_runtime.h>

typedef unsigned short u16t;
typedef __bf16 bf16x8 __attribute__((ext_vector_type(8)));
typedef float  f32x4  __attribute__((ext_vector_type(4)));
typedef float  f32x16 __attribute__((ext_vector_type(16)));
typedef unsigned u32x2 __attribute__((ext_vector_type(2)));
typedef unsigned u32x4 __attribute__((ext_vector_type(4)));

#define DEV __device__ __forceinline__

DEV u16t f32_to_bf16(float f) {
    unsigned u = __float_as_uint(f);
    unsigned r = (u + 0x7FFFu + ((u >> 16) & 1u)) >> 16;   // RNE
    return (u16t)r;
}
DEV float bf16_to_f32(u16t u) { return __uint_as_float((unsigned)u << 16); }

DEV unsigned cvt_pk_bf16(float lo, float hi) {
    unsigned r;
    asm("v_cvt_pk_bf16_f32 %0, %1, %2" : "=v"(r) : "v"(lo), "v"(hi));
    return r;
}

DEV float gelu_exact(float x) {
    return 0.5f * x * (1.0f + erff(x * 0.70710678118654752f));
}

DEV void glds16(const void* g, void* l) {
    __builtin_amdgcn_global_load_lds(
        (const __attribute__((address_space(1))) void*)g,
        (__attribute__((address_space(3))) void*)l, 16, 0, 0);
}

// counted-wait + raw barrier pair (never drain in-flight prefetch)
#define WAITN_BARRIER(N)                                          \
    asm volatile("s_waitcnt vmcnt(" #N ")" ::: "memory");         \
    __builtin_amdgcn_sched_barrier(0);                            \
    __builtin_amdgcn_s_barrier();                                 \
    __builtin_amdgcn_sched_barrier(0);

#define PLAIN_BARRIER()                                           \
    __builtin_amdgcn_sched_barrier(0);                            \
    __builtin_amdgcn_s_barrier();

// ---------------------------------------------------------------- LayerNorm
__global__ __launch_bounds__(256)
void ln_kernel(const float* __restrict__ x, const float* __restrict__ g,
               const float* __restrict__ b, u16t* __restrict__ out)
{
    const int row = blockIdx.x;
    const int t = threadIdx.x;
    const float* xr = x + (size_t)row * 768;
    float v0 = xr[t], v1 = xr[t + 256], v2 = xr[t + 512];
    float s = v0 + v1 + v2;
    float s2 = v0 * v0 + v1 * v1 + v2 * v2;
#pragma unroll
    for (int off = 32; off > 0; off >>= 1) {
        s  += __shfl_xor(s, off);
        s2 += __shfl_xor(s2, off);
    }
    __shared__ float sm[8];
    const int w = t >> 6;
    if ((t & 63) == 0) { sm[w] = s; sm[4 + w] = s2; }
    __syncthreads();
    s  = sm[0] + sm[1] + sm[2] + sm[3];
    s2 = sm[4] + sm[5] + sm[6] + sm[7];
    const float mu  = s * (1.0f / 768.0f);
    const float var = fmaxf(s2 * (1.0f / 768.0f) - mu * mu, 0.0f);
    const float rst = rsqrtf(var + 1e-5f);
    u16t* o = out + (size_t)row * 768;
    o[t]       = f32_to_bf16((v0 - mu) * rst * g[t]       + b[t]);
    o[t + 256] = f32_to_bf16((v1 - mu) * rst * g[t + 256] + b[t + 256]);
    o[t + 512] = f32_to_bf16((v2 - mu) * rst * g[t + 512] + b[t + 512]);
}

// ---------------------------------------------------- transpose f32 -> bf16
__global__ __launch_bounds__(256)
void transpose_cast(const float* __restrict__ in, u16t* __restrict__ out,
                    int R, int C)
{
    __shared__ float tile[64][65];
    const int c0 = blockIdx.x * 64, r0 = blockIdx.y * 64;
    const int t = threadIdx.x;
#pragma unroll
    for (int j = 0; j < 16; ++j) {
        const int idx = j * 256 + t;
        const int rl = idx >> 6, cl = idx & 63;
        tile[rl][cl] = in[(size_t)(r0 + rl) * C + c0 + cl];
    }
    __syncthreads();
#pragma unroll
    for (int j = 0; j < 16; ++j) {
        const int idx = j * 256 + t;
        const int cl = idx >> 6, rl = idx & 63;
        out[(size_t)(c0 + cl) * R + r0 + rl] = f32_to_bf16(tile[rl][cl]);
    }
}

// ------------------------------------------------------------------- GEMM
// C[M,N] = A[M,K] * BT[N,K]^T, bf16 in, 128x128 tile, BK=32, double-buffered
// LDS with counted vmcnt(4) + raw barriers; 64B-row XOR swizzle (both sides).
// MODE 0: f32. MODE 1: +res(+bias) f32. MODE 2: gelu(acc+bias) bf16.
// MODE 3: qkv epilogue -> Q,K [B*H,N,64] bf16 + VT [B*H,64,N].
template <int MODE>
__global__ __launch_bounds__(256)
void gemm_kernel(const u16t* __restrict__ A, const u16t* __restrict__ BT,
                 float* __restrict__ Cf, u16t* __restrict__ Cb,
                 const float* __restrict__ bias, const float* __restrict__ res,
                 u16t* __restrict__ Qo, u16t* __restrict__ Ko,
                 u16t* __restrict__ VTo,
                 int M, int Nn, int K)
{
    // per buffer: A [128][32] bf16 8KB | B [128][32] bf16 8KB; two buffers
    __shared__ __align__(16) char gsm[32768];
    const int t = threadIdx.x;
    const int w = t >> 6, lane = t & 63;
    const int l16 = lane & 15, lhi = lane >> 4;
    const int wr = w >> 1, wc = w & 1;
    const int m0 = blockIdx.x * 128, n0 = blockIdx.y * 128;

    const f32x4 fz = {0.f, 0.f, 0.f, 0.f};
    f32x4 acc[4][4];
#pragma unroll
    for (int i = 0; i < 4; ++i)
#pragma unroll
        for (int j = 0; j < 4; ++j) acc[i][j] = fz;

    // staging constants: rows of 64B (32 bf16), slot = 16B unit
    const int srow = lane >> 2;                              // 0..15 per instr
    const int sslot = ((lane & 3) ^ ((lane >> 3) & 3)) * 16; // pre-swizzled
    // read-side swizzle (row = 64*wx+16i+l16 -> (row>>1)&3 == (l16>>1)&3)
    const int aswz = ((lhi ^ ((l16 >> 1) & 3)) << 4);

    auto stage = [&](int bufb, int kt) {
#pragma unroll
        for (int i = 0; i < 2; ++i) {
            const int row = w * 32 + i * 16 + srow;
            glds16((const char*)A + ((size_t)(m0 + row) * K + kt) * 2 + sslot,
                   gsm + bufb + w * 2048 + i * 1024);
            glds16((const char*)BT + ((size_t)(n0 + row) * K + kt) * 2 + sslot,
                   gsm + bufb + 8192 + w * 2048 + i * 1024);
        }
    };

    auto body = [&](int bufb) {
        const char* Ab = gsm + bufb;
        const char* Bb = gsm + bufb + 8192;
        bf16x8 af[4], bfv[4];
#pragma unroll
        for (int i = 0; i < 4; ++i)
            af[i] = *reinterpret_cast<const bf16x8*>(
                Ab + (64 * wr + 16 * i + l16) * 64 + aswz);
#pragma unroll
        for (int j = 0; j < 4; ++j)
            bfv[j] = *reinterpret_cast<const bf16x8*>(
                Bb + (64 * wc + 16 * j + l16) * 64 + aswz);
#pragma unroll
        for (int i = 0; i < 4; ++i)
#pragma unroll
            for (int j = 0; j < 4; ++j)
                acc[i][j] = __builtin_amdgcn_mfma_f32_16x16x32_bf16(
                    af[i], bfv[j], acc[i][j], 0, 0, 0);
    };

    stage(0, 0);
    int bufb = 0;
    for (int kt = 0; kt + 32 < K; kt += 32) {
        stage(bufb ^ 16384, kt + 32);
        WAITN_BARRIER(4)
        body(bufb);
        PLAIN_BARRIER()
        bufb ^= 16384;
    }
    WAITN_BARRIER(0)
    body(bufb);

    const int rb = m0 + 64 * wr + 4 * lhi;
    const int cb = n0 + 64 * wc + l16;

    if (MODE == 3) {
        const int qi = n0 / 768;                 // uniform per block
        const int b = rb >> 11;
        const int nn0 = rb & 2047;
#pragma unroll
        for (int j = 0; j < 4; ++j) {
            const int c = cb - qi * 768 + 16 * j;   // 0..767
            const int h = c >> 6, d = c & 63;
            if (qi < 2) {
                u16t* dst = (qi == 0) ? Qo : Ko;
                const size_t base = ((size_t)(b * 12 + h) * 2048 + nn0) * 64 + d;
#pragma unroll
                for (int i = 0; i < 4; ++i)
#pragma unroll
                    for (int r = 0; r < 4; ++r)
                        dst[base + (size_t)(16 * i + r) * 64] =
                            f32_to_bf16(acc[i][j][r]);
            } else {
                u16t* dst = VTo + ((size_t)(b * 12 + h) * 64 + d) * 2048 + nn0;
#pragma unroll
                for (int i = 0; i < 4; ++i) {
                    u32x2 pr;
                    pr[0] = cvt_pk_bf16(acc[i][j][0], acc[i][j][1]);
                    pr[1] = cvt_pk_bf16(acc[i][j][2], acc[i][j][3]);
                    *reinterpret_cast<u32x2*>(dst + 16 * i) = pr;
                }
            }
        }
        return;
    }

#pragma unroll
    for (int i = 0; i < 4; ++i) {
#pragma unroll
        for (int j = 0; j < 4; ++j) {
#pragma unroll
            for (int r = 0; r < 4; ++r) {
                const int row = rb + 16 * i + r;
                const int col = cb + 16 * j;
                float v = acc[i][j][r];
                if (MODE == 0) {
                    Cf[(size_t)row * Nn + col] = v;
                } else if (MODE == 1) {
                    v += res[(size_t)row * Nn + col];
                    if (bias) v += bias[col];
                    Cf[(size_t)row * Nn + col] = v;
                } else if (MODE == 2) {
                    v = gelu_exact(v + bias[col]);
                    Cb[(size_t)row * Nn + col] = f32_to_bf16(v);
                }
            }
        }
    }
}

// ------------------------------------------------------- flash attention
// Swapped-operand 32x32 MFMA; ALL streams (bias/K/V) LDS-staged coalesced,
// double-buffered, counted vmcnt(6) + raw barriers. Max-free softmax,
// 2-way k-split. grid (16, B*H, 2), block 256 (4 waves x 32 q-rows).
__global__ __launch_bounds__(256)
void attn_kernel(const u16t* __restrict__ Q, const u16t* __restrict__ K,
                 const u16t* __restrict__ VT, const float* __restrict__ bias,
                 u16t* __restrict__ Opart, float* __restrict__ Lpart)
{
    const int SEQ = 2048;
    const int bh = blockIdx.y, h = bh % 12;
    const int ks = blockIdx.z;
    const int t = threadIdx.x;
    const int w = t >> 6, lane = t & 63;
    const int l32 = lane & 31, hi = lane >> 5;
    const int q = blockIdx.x * 128 + w * 32 + l32;

    // per buffer (24KB): [0,16K) bias [128q][128B f32=32k] swz(row&7)
    //                    [16K,20K) K [32k][128B] swz(row&7)
    //                    [20K,24K) V [64d][64B] swz((row>>1)&3)
    __shared__ __align__(16) char smem[49152];

    const u16t* qp = Q + ((size_t)bh * SEQ + q) * 64 + 8 * hi;
    bf16x8 qf[4];
#pragma unroll
    for (int dseg = 0; dseg < 4; ++dseg)
        qf[dseg] = *reinterpret_cast<const bf16x8*>(qp + dseg * 16);

    const char* kg = (const char*)K + (size_t)bh * SEQ * 128;       // 128B rows
    const char* vg = (const char*)VT + (size_t)bh * 64 * 4096;      // 4KB rows
    const char* bg = (const char*)bias +
                     ((size_t)h * SEQ + blockIdx.x * 128) * 8192;   // 8KB rows

    // staging lane constants (pre-swizzled global source, linear LDS dest)
    const int srow8 = lane >> 3;                        // 0..7
    const int sslotK = ((lane & 7) ^ srow8) * 16;       // 128B-row swizzle
    const int vrow  = w * 16 + (lane >> 2);             // 0..63
    const int sslotV = ((lane & 3) ^ ((vrow >> 1) & 3)) * 16;

    auto stage = [&](int bufb, int k0) {                // exactly 6 VMEM ops
#pragma unroll
        for (int i = 0; i < 4; ++i) {
            const int row = 32 * w + 8 * i + srow8;
            glds16(bg + (size_t)row * 8192 + (size_t)k0 * 4 + sslotK,
                   smem + bufb + 32 * w * 128 + i * 1024);
        }
        glds16(kg + (size_t)(k0 + 8 * w + srow8) * 128 + sslotK,
               smem + bufb + 16384 + w * 1024);
        glds16(vg + (size_t)vrow * 4096 + (size_t)k0 * 2 + sslotV,
               smem + bufb + 20480 + w * 1024);
    };

    // read-side swizzled offsets (loop-invariant)
    const int rsw = l32 & 7;
    int boff[4], koff[4];
#pragma unroll
    for (int g = 0; g < 4; ++g)
        boff[g] = (32 * w + l32) * 128 + ((((g << 1) + hi) ^ rsw) << 4);
#pragma unroll
    for (int dseg = 0; dseg < 4; ++dseg)
        koff[dseg] = 16384 + l32 * 128 + ((((dseg << 1) + hi) ^ rsw) << 4);
    const int vr3 = (l32 >> 1) & 3;
    const int voff00 = 20480 + l32 * 64 + ((hi ^ vr3) << 4);
    const int voff01 = 20480 + l32 * 64 + (((2 + hi) ^ vr3) << 4);
    const int voff10 = voff00 + 32 * 64;
    const int voff11 = voff01 + 32 * 64;

    f32x16 o0, o1;
#pragma unroll
    for (int i = 0; i < 16; ++i) { o0[i] = 0.f; o1[i] = 0.f; }
    float lsum = 0.f;

    auto body = [&](int bufb) {
        const char* bb = smem + bufb;
        f32x4 bv[4];
#pragma unroll
        for (int g = 0; g < 4; ++g)
            bv[g] = *reinterpret_cast<const f32x4*>(bb + boff[g]);
        f32x16 st;
#pragma unroll
        for (int i = 0; i < 16; ++i) st[i] = 0.f;
#pragma unroll
        for (int dseg = 0; dseg < 4; ++dseg) {
            bf16x8 kf = *reinterpret_cast<const bf16x8*>(bb + koff[dseg]);
            st = __builtin_amdgcn_mfma_f32_32x32x16_bf16(kf, qf[dseg], st, 0, 0, 0);
        }
        unsigned pk[8];
#pragma unroll
        for (int i2 = 0; i2 < 8; ++i2) {
            const int ia = 2 * i2, ib = 2 * i2 + 1;
            const float pa = __expf(st[ia] * 0.125f + bv[ia >> 2][ia & 3]);
            const float pb = __expf(st[ib] * 0.125f + bv[ib >> 2][ib & 3]);
            lsum += pa + pb;
            pk[i2] = cvt_pk_bf16(pa, pb);
        }
        unsigned sx[8];
#pragma unroll
        for (int i2 = 0; i2 < 8; ++i2)
            sx[i2] = (unsigned)__shfl_xor((int)pk[i2], 32);
        union { unsigned u[4]; bf16x8 v; } B0, B1;
        B0.u[0] = hi ? sx[2] : pk[0];
        B0.u[1] = hi ? sx[3] : pk[1];
        B0.u[2] = hi ? pk[2] : sx[0];
        B0.u[3] = hi ? pk[3] : sx[1];
        B1.u[0] = hi ? sx[6] : pk[4];
        B1.u[1] = hi ? sx[7] : pk[5];
        B1.u[2] = hi ? pk[6] : sx[4];
        B1.u[3] = hi ? pk[7] : sx[5];
        bf16x8 v00 = *reinterpret_cast<const bf16x8*>(bb + voff00);
        bf16x8 v01 = *reinterpret_cast<const bf16x8*>(bb + voff01);
        bf16x8 v10 = *reinterpret_cast<const bf16x8*>(bb + voff10);
        bf16x8 v11 = *reinterpret_cast<const bf16x8*>(bb + voff11);
        o0 = __builtin_amdgcn_mfma_f32_32x32x16_bf16(v00, B0.v, o0, 0, 0, 0);
        o0 = __builtin_amdgcn_mfma_f32_32x32x16_bf16(v01, B1.v, o0, 0, 0, 0);
        o1 = __builtin_amdgcn_mfma_f32_32x32x16_bf16(v10, B0.v, o1, 0, 0, 0);
        o1 = __builtin_amdgcn_mfma_f32_32x32x16_bf16(v11, B1.v, o1, 0, 0, 0);
    };

    const int kbeg = ks * 1024;
    stage(0, kbeg);
    int bufb = 0;
    for (int k0 = kbeg; k0 < kbeg + 1024 - 32; k0 += 32) {
        stage(bufb ^ 24576, k0 + 32);
        WAITN_BARRIER(6)
        body(bufb);
        PLAIN_BARRIER()
        bufb ^= 24576;
    }
    WAITN_BARRIER(0)
    body(bufb);

    lsum += __shfl_xor(lsum, 32);

    u16t* op = Opart + ((size_t)(ks * 24 + bh) * SEQ + q) * 64;
#pragma unroll
    for (int dh = 0; dh < 2; ++dh) {
        const f32x16& o = dh ? o1 : o0;
#pragma unroll
        for (int g = 0; g < 4; ++g) {
            u32x2 pr;
            pr[0] = cvt_pk_bf16(o[4 * g], o[4 * g + 1]);
            pr[1] = cvt_pk_bf16(o[4 * g + 2], o[4 * g + 3]);
            *reinterpret_cast<u32x2*>(op + dh * 32 + 8 * g + 4 * hi) = pr;
        }
    }
    if (!hi)
        Lpart[(size_t)(ks * 24 + bh) * SEQ + q] = lsum;
}

// --------------------------------------------- combine k-split partials
__global__ __launch_bounds__(256)
void attn_combine(const u16t* __restrict__ Opart,
                  const float* __restrict__ Lpart, u16t* __restrict__ out)
{
    const int idx = blockIdx.x * 256 + threadIdx.x;   // 0 .. 24*2048*8
    const int dg = idx & 7;
    const int q = (idx >> 3) & 2047;
    const int bh = idx >> 14;
    const int b = bh / 12, h = bh % 12;
    const size_t base = ((size_t)bh * 2048 + q) * 64 + dg * 8;
    const size_t stride = (size_t)24 * 2048 * 64;
    float acc[8] = {0.f, 0.f, 0.f, 0.f, 0.f, 0.f, 0.f, 0.f};
    float l = 0.f;
#pragma unroll
    for (int j = 0; j < 2; ++j) {
        const u32x4 a = *reinterpret_cast<const u32x4*>(Opart + base + j * stride);
#pragma unroll
        for (int m = 0; m < 4; ++m) {
            acc[2 * m]     += bf16_to_f32((u16t)(a[m] & 0xFFFF));
            acc[2 * m + 1] += bf16_to_f32((u16t)(a[m] >> 16));
        }
        l += Lpart[(size_t)j * 24 * 2048 + bh * 2048 + q];
    }
    const float inv = 1.0f / l;
    u32x4 r;
#pragma unroll
    for (int m = 0; m < 4; ++m)
        r[m] = cvt_pk_bf16(acc[2 * m] * inv, acc[2 * m + 1] * inv);
    *reinterpret_cast<u32x4*>(
        out + ((size_t)(b * 2048 + q)) * 768 + h * 64 + dg * 8) = r;
}

// ------------------------------------------------------------------ launch
extern "C" void kernel_launch(void* const* d_in, const int* in_sizes, int n_in,
                              void* d_out, int out_size, void* d_ws, size_t ws_size,
                              hipStream_t stream)
{
    const float* x    = (const float*)d_in[0];
    const float* Wqkv = (const float*)d_in[1];
    const float* Wout = (const float*)d_in[2];
    const float* g1   = (const float*)d_in[3];
    const float* be1  = (const float*)d_in[4];
    const float* g2   = (const float*)d_in[5];
    const float* be2  = (const float*)d_in[6];
    const float* W1   = (const float*)d_in[7];
    const float* b1   = (const float*)d_in[8];
    const float* W2   = (const float*)d_in[9];
    const float* b2   = (const float*)d_in[10];
    const float* ab   = (const float*)d_in[11];
    float* outp = (float*)d_out;

    char* ws = (char*)d_ws;
    size_t off = 0;
    auto alloc = [&](size_t bytes) -> char* {
        char* p = ws + off;
        off += (bytes + 255) & ~(size_t)255;
        return p;
    };

    u16t* WqkvT = (u16t*)alloc((size_t)2304 * 768 * 2);
    u16t* WoutT = (u16t*)alloc((size_t)768 * 768 * 2);
    u16t* W1T   = (u16t*)alloc((size_t)3072 * 768 * 2);
    u16t* W2T   = (u16t*)alloc((size_t)768 * 3072 * 2);
    u16t* h1    = (u16t*)alloc((size_t)4096 * 768 * 2);
    u16t* Qb    = (u16t*)alloc((size_t)24 * 2048 * 64 * 2);
    u16t* Kb    = (u16t*)alloc((size_t)24 * 2048 * 64 * 2);
    u16t* VTb   = (u16t*)alloc((size_t)24 * 64 * 2048 * 2);
    u16t* attnb = (u16t*)alloc((size_t)4096 * 768 * 2);
    float* x1   = (float*)alloc((size_t)4096 * 768 * 4);
    u16t* h2    = (u16t*)alloc((size_t)4096 * 768 * 2);
    u16t* Opart = (u16t*)alloc((size_t)2 * 24 * 2048 * 64 * 2);
    float* Lpart = (float*)alloc((size_t)2 * 24 * 2048 * 4);
    u16t* act   = (u16t*)alloc((size_t)4096 * 3072 * 2);

    // weight prep
    transpose_cast<<<dim3(36, 12), 256, 0, stream>>>(Wqkv, WqkvT, 768, 2304);
    transpose_cast<<<dim3(12, 12), 256, 0, stream>>>(Wout, WoutT, 768, 768);
    transpose_cast<<<dim3(48, 12), 256, 0, stream>>>(W1,   W1T,   768, 3072);
    transpose_cast<<<dim3(12, 48), 256, 0, stream>>>(W2,   W2T,   3072, 768);

    // attention block
    ln_kernel<<<4096, 256, 0, stream>>>(x, g1, be1, h1);
    gemm_kernel<3><<<dim3(32, 18), 256, 0, stream>>>(
        h1, WqkvT, nullptr, nullptr, nullptr, nullptr, Qb, Kb, VTb,
        4096, 2304, 768);
    attn_kernel<<<dim3(16, 24, 2), 256, 0, stream>>>(Qb, Kb, VTb, ab, Opart, Lpart);
    attn_combine<<<(24 * 2048 * 8) / 256, 256, 0, stream>>>(Opart, Lpart, attnb);
    gemm_kernel<1><<<dim3(32, 6), 256, 0, stream>>>(
        attnb, WoutT, x1, nullptr, nullptr, x, nullptr, nullptr, nullptr,
        4096, 768, 768);

    // feed-forward block
    ln_kernel<<<4096, 256, 0, stream>>>(x1, g2, be2, h2);
    gemm_kernel<2><<<dim3(32, 24), 256, 0, stream>>>(
        h2, W1T, nullptr, act, b1, nullptr, nullptr, nullptr, nullptr,
        4096, 3072, 768);
    gemm_kernel<1><<<dim3(32, 6), 256, 0, stream>>>(
        act, W2T, outp, nullptr, b2, x1, nullptr, nullptr, nullptr,
        4096, 768, 3072);
}